// Round 1
// baseline (1827.390 us; speedup 1.0000x reference)
//
#include <hip/hip_runtime.h>
#include <math.h>

#define BB 2
#define CC 512
#define HEADS 2
#define DH 256
#define NWIN 64
#define LTOT 4096
#define TP 3
#define LP 3
#define SCALE 0.0625f

__device__ __forceinline__ int refl8(int v) {
  v = v < 0 ? -v : v;
  return v >= 8 ? 14 - v : v;
}

// Y[b,o,p] = sum_c W[o,c] * X[b,c,p] + bias[o]
__global__ __launch_bounds__(256) void conv1x1_kernel(
    const float* __restrict__ X, const float* __restrict__ Wm,
    const float* __restrict__ bias, float* __restrict__ Y, int Cout) {
  int blocksPerB = Cout >> 2;
  int b = blockIdx.x / blocksPerB;
  int ob = blockIdx.x - b * blocksPerB;
  int o = ob * 4 + (threadIdx.x >> 6);
  int p = threadIdx.x & 63;
  const float* xb = X + (size_t)b * CC * 64;
  const float* wr = Wm + (size_t)o * CC;
  float acc = 0.f;
#pragma unroll 8
  for (int c = 0; c < CC; ++c) acc += wr[c] * xb[c * 64 + p];
  Y[((size_t)b * Cout + o) * 64 + p] = acc + bias[o];
}

// One block per (b, win, head). Computes local window attention -> qg (B,h,L,d)
__global__ __launch_bounds__(256) void local_attn_kernel(
    const float* __restrict__ qkvx, const float* __restrict__ qkz,
    const float* __restrict__ pbeta, float* __restrict__ qg) {
  __shared__ float kbuf[128 * 64];  // half of K^T: [dd_local][tok]
  __shared__ float att[64 * 65];    // logits / probs, padded stride 65
  int bid = blockIdx.x;  // 256 = B * 64 * 2
  int b = bid >> 7;
  int win = (bid & 127) >> 1;
  int head = bid & 1;
  int tid = threadIdx.x;
  int t = tid & 63;   // token
  int w4 = tid >> 6;  // 0..3 (wave id)
  int wi = win >> 3, wj = win & 7;
  int ry = refl8(wi + (t >> 3) - TP);
  int rx = refl8(wj + (t & 7) - LP);
  int pix = ry * 8 + rx;
  float beta = log1pf(__expf(pbeta[0])) + 1e-6f;

  const float* qxb = qkvx + (size_t)(b * 1536 + head * DH) * 64;
  const float* kxb = qkvx + (size_t)(b * 1536 + 512 + head * DH) * 64;
  const float* vxb = qkvx + (size_t)(b * 1536 + 1024 + head * DH) * 64;
  const float* qzb = qkz + (size_t)(b * 1024 + head * DH) * 64;
  const float* kzb = qkz + (size_t)(b * 1024 + 512 + head * DH) * 64;

  float dots[16];
  // ---- lx = qx . kx ----
#pragma unroll
  for (int s = 0; s < 16; ++s) dots[s] = 0.f;
#pragma unroll
  for (int hf = 0; hf < 2; ++hf) {
    __syncthreads();
    for (int i = 0; i < 32; ++i) {
      int dd = i * 4 + w4;
      kbuf[dd * 64 + t] = kxb[(hf * 128 + dd) * 64 + pix];
    }
    __syncthreads();
    for (int dd = 0; dd < 128; ++dd) {
      float qv = qxb[(hf * 128 + dd) * 64 + pix];
#pragma unroll
      for (int s = 0; s < 16; ++s)
        dots[s] += qv * kbuf[dd * 64 + w4 * 16 + s];
    }
  }
#pragma unroll
  for (int s = 0; s < 16; ++s) att[t * 65 + w4 * 16 + s] = dots[s];
  // ---- lz = qz . kz, combine ----
#pragma unroll
  for (int s = 0; s < 16; ++s) dots[s] = 0.f;
#pragma unroll
  for (int hf = 0; hf < 2; ++hf) {
    __syncthreads();
    for (int i = 0; i < 32; ++i) {
      int dd = i * 4 + w4;
      kbuf[dd * 64 + t] = kzb[(hf * 128 + dd) * 64 + pix];
    }
    __syncthreads();
    for (int dd = 0; dd < 128; ++dd) {
      float qv = qzb[(hf * 128 + dd) * 64 + pix];
#pragma unroll
      for (int s = 0; s < 16; ++s)
        dots[s] += qv * kbuf[dd * 64 + w4 * 16 + s];
    }
  }
#pragma unroll
  for (int s = 0; s < 16; ++s) {
    int ii = t * 65 + w4 * 16 + s;
    att[ii] = SCALE * (att[ii] + beta * dots[s]);
  }
  __syncthreads();
  // ---- row softmax (64 rows by first 64 threads) ----
  if (tid < 64) {
    float m = -1e30f;
    for (int s = 0; s < 64; ++s) m = fmaxf(m, att[tid * 65 + s]);
    float den = 0.f;
    for (int s = 0; s < 64; ++s) den += __expf(att[tid * 65 + s] - m);
    float r = 1.f / den;
    for (int s = 0; s < 64; ++s) att[tid * 65 + s] = __expf(att[tid * 65 + s] - m) * r;
  }
  // ---- out = A @ V ----
  float acc[64];
#pragma unroll
  for (int j = 0; j < 64; ++j) acc[j] = 0.f;
#pragma unroll
  for (int hf = 0; hf < 2; ++hf) {
    __syncthreads();
    for (int i = 0; i < 32; ++i) {
      int dd = i * 4 + w4;
      kbuf[dd * 64 + t] = vxb[(hf * 128 + dd) * 64 + pix];
    }
    __syncthreads();
    for (int s = 0; s < 64; ++s) {
      float av = att[t * 65 + s];
#pragma unroll
      for (int j = 0; j < 32; ++j)
        acc[hf * 32 + j] += av * kbuf[(w4 * 32 + j) * 64 + s];
    }
  }
  float* dst = qg + ((size_t)((b * HEADS + head) * LTOT + win * 64 + t)) * DH;
#pragma unroll
  for (int j = 0; j < 32; ++j) {
    dst[w4 * 32 + j] = acc[j];
    dst[128 + w4 * 32 + j] = acc[32 + j];
  }
}

// Global self-attention: og = softmax(qg qg^T * scale) qg, per (b,h).
// One block = 32 queries; thread = (query, 8-way dim split of 256).
__global__ __launch_bounds__(256) void gattn_kernel(
    const float* __restrict__ qg, float* __restrict__ og) {
  __shared__ float ktile[32 * DH];  // 32 keys x 256 dims, 32 KB
  int bh = blockIdx.x >> 7;
  int qblk = blockIdx.x & 127;
  int tid = threadIdx.x;
  int qsl = tid >> 3;  // 0..31
  int oct = tid & 7;   // 0..7 -> dim slice interleaved by 4: D = g*32 + oct*4 + j
  int qi = qblk * 32 + qsl;
  const float* base = qg + (size_t)bh * LTOT * DH;
  float qreg[32], acc[32];
#pragma unroll
  for (int g = 0; g < 8; ++g) {
    float4 qv = *(const float4*)(base + (size_t)qi * DH + g * 32 + oct * 4);
    qreg[g * 4 + 0] = qv.x; qreg[g * 4 + 1] = qv.y;
    qreg[g * 4 + 2] = qv.z; qreg[g * 4 + 3] = qv.w;
  }
#pragma unroll
  for (int i = 0; i < 32; ++i) acc[i] = 0.f;
  float m = -1e30f, l = 0.f;
  for (int kt = 0; kt < 128; ++kt) {
    __syncthreads();
    {
      const float4* src4 = (const float4*)(base + (size_t)(kt * 32) * DH);
      float4* kt4 = (float4*)ktile;
#pragma unroll
      for (int it = 0; it < 8; ++it)
        kt4[it * 256 + tid] = src4[it * 256 + tid];
    }
    __syncthreads();
    for (int s = 0; s < 32; ++s) {
      float kreg[32];
#pragma unroll
      for (int g = 0; g < 8; ++g) {
        float4 kv = *(const float4*)(&ktile[s * DH + g * 32 + oct * 4]);
        kreg[g * 4 + 0] = kv.x; kreg[g * 4 + 1] = kv.y;
        kreg[g * 4 + 2] = kv.z; kreg[g * 4 + 3] = kv.w;
      }
      float part = 0.f;
#pragma unroll
      for (int i = 0; i < 32; ++i) part += qreg[i] * kreg[i];
      part += __shfl_xor(part, 1, 64);
      part += __shfl_xor(part, 2, 64);
      part += __shfl_xor(part, 4, 64);
      float sc = part * SCALE;
      float mn = fmaxf(m, sc);
      float corr = __expf(m - mn);
      float p = __expf(sc - mn);
      l = l * corr + p;
#pragma unroll
      for (int i = 0; i < 32; ++i) acc[i] = acc[i] * corr + p * kreg[i];
      m = mn;
    }
  }
  float r = 1.f / l;
  float* dst = og + (size_t)bh * LTOT * DH + (size_t)qi * DH;
#pragma unroll
  for (int g = 0; g < 8; ++g)
#pragma unroll
    for (int j = 0; j < 4; ++j)
      dst[g * 32 + oct * 4 + j] = acc[g * 4 + j] * r;
}

// Overlap-add (gather form), divide by counts, crop -> crop (B,C,64) layout [b][c][p]
__global__ __launch_bounds__(256) void overlap_kernel(
    const float* __restrict__ og, float* __restrict__ crop) {
  int idx = blockIdx.x * 256 + threadIdx.x;  // 65536 = B*h*64*256
  int dim = idx & 255;
  int r = idx >> 8;
  int p = r & 63;
  int head = (r >> 6) & 1;
  int b = r >> 7;
  int y = p >> 3, x = p & 7;
  int py = y + TP, px = x + LP;
  int i0 = max(0, py - 7), i1 = min(7, py);
  int j0 = max(0, px - 7), j1 = min(7, px);
  float s = 0.f;
  const float* basep = og + (size_t)(b * HEADS + head) * LTOT * DH;
  for (int iw = i0; iw <= i1; ++iw)
    for (int jw = j0; jw <= j1; ++jw) {
      int tok = (py - iw) * 8 + (px - jw);
      s += basep[(size_t)((iw * 8 + jw) * 64 + tok) * DH + dim];
    }
  float cnt = (float)((i1 - i0 + 1) * (j1 - j0 + 1));
  crop[((size_t)b * CC + head * DH + dim) * 64 + p] = s / (cnt + 1e-6f);
}

// out = x_feat + a * (Wproj @ crop + bproj)
__global__ __launch_bounds__(256) void final_kernel(
    const float* __restrict__ crop, const float* __restrict__ Wp,
    const float* __restrict__ bp, const float* __restrict__ x_feat,
    const float* __restrict__ pa, float* __restrict__ out) {
  int blocksPerB = CC >> 2;  // 128
  int b = blockIdx.x / blocksPerB;
  int ob = blockIdx.x - b * blocksPerB;
  int o = ob * 4 + (threadIdx.x >> 6);
  int p = threadIdx.x & 63;
  float a = 2.f / (1.f + __expf(-pa[0]));
  const float* xb = crop + (size_t)b * CC * 64;
  const float* wr = Wp + (size_t)o * CC;
  float acc = 0.f;
#pragma unroll 8
  for (int c = 0; c < CC; ++c) acc += wr[c] * xb[c * 64 + p];
  size_t oi = ((size_t)b * CC + o) * 64 + p;
  out[oi] = x_feat[oi] + a * (acc + bp[o]);
}

extern "C" void kernel_launch(void* const* d_in, const int* in_sizes, int n_in,
                              void* d_out, int out_size, void* d_ws, size_t ws_size,
                              hipStream_t stream) {
  const float* x_feat = (const float*)d_in[0];
  const float* z_feat = (const float*)d_in[1];
  const float* Wqkv = (const float*)d_in[2];
  const float* bqkv = (const float*)d_in[3];
  const float* Wqkz = (const float*)d_in[4];
  const float* bqkz = (const float*)d_in[5];
  const float* Wproj = (const float*)d_in[6];
  const float* bproj = (const float*)d_in[7];
  const float* pa = (const float*)d_in[8];
  const float* pbeta = (const float*)d_in[9];
  float* ws = (float*)d_ws;
  float* qkvx = ws;                  // B*1536*64 = 196608
  float* qkz = ws + 196608;          // B*1024*64 = 131072
  float* qg = ws + 327680;           // B*h*L*d = 4194304
  float* og = ws + 4521984;          // 4194304
  float* crop = ws + 8716288;        // 65536   (total 8781824 floats = 35.2 MB)
  float* out = (float*)d_out;

  conv1x1_kernel<<<BB * (1536 / 4), 256, 0, stream>>>(x_feat, Wqkv, bqkv, qkvx, 1536);
  conv1x1_kernel<<<BB * (1024 / 4), 256, 0, stream>>>(z_feat, Wqkz, bqkz, qkz, 1024);
  local_attn_kernel<<<256, 256, 0, stream>>>(qkvx, qkz, pbeta, qg);
  gattn_kernel<<<512, 256, 0, stream>>>(qg, og);
  overlap_kernel<<<256, 256, 0, stream>>>(og, crop);
  final_kernel<<<BB * (CC / 4), 256, 0, stream>>>(crop, Wproj, bproj, x_feat, pa, out);
}

// Round 2
// 423.265 us; speedup vs baseline: 4.3174x; 4.3174x over previous
//
#include <hip/hip_runtime.h>
#include <math.h>

#define BB 2
#define CC 512
#define HEADS 2
#define DH 256
#define NWIN 64
#define LTOT 4096
#define TP 3
#define LP 3
#define SCALE 0.0625f

typedef short bf16x8 __attribute__((ext_vector_type(8)));
typedef float f32x4 __attribute__((ext_vector_type(4)));

__device__ __forceinline__ int refl8(int v) {
  v = v < 0 ? -v : v;
  return v >= 8 ? 14 - v : v;
}

__device__ __forceinline__ unsigned int bf16rne(float x) {
  unsigned int u = __float_as_uint(x);
  return (u + 0x7fffu + ((u >> 16) & 1u)) >> 16;
}

// Y[b,o,p] = sum_c W[o,c] * X[b,c,p] + bias[o]
__global__ __launch_bounds__(256) void conv1x1_kernel(
    const float* __restrict__ X, const float* __restrict__ Wm,
    const float* __restrict__ bias, float* __restrict__ Y, int Cout) {
  int blocksPerB = Cout >> 2;
  int b = blockIdx.x / blocksPerB;
  int ob = blockIdx.x - b * blocksPerB;
  int o = ob * 4 + (threadIdx.x >> 6);
  int p = threadIdx.x & 63;
  const float* xb = X + (size_t)b * CC * 64;
  const float* wr = Wm + (size_t)o * CC;
  float acc = 0.f;
#pragma unroll 8
  for (int c = 0; c < CC; ++c) acc += wr[c] * xb[c * 64 + p];
  Y[((size_t)b * Cout + o) * 64 + p] = acc + bias[o];
}

// One block per (b, win, head). Local window attention -> qgb (B,h,L,d) in bf16
__global__ __launch_bounds__(256) void local_attn_kernel(
    const float* __restrict__ qkvx, const float* __restrict__ qkz,
    const float* __restrict__ pbeta, unsigned short* __restrict__ qgb) {
  __shared__ float kbuf[128 * 64];
  __shared__ float att[64 * 65];
  int bid = blockIdx.x;
  int b = bid >> 7;
  int win = (bid & 127) >> 1;
  int head = bid & 1;
  int tid = threadIdx.x;
  int t = tid & 63;
  int w4 = tid >> 6;
  int wi = win >> 3, wj = win & 7;
  int ry = refl8(wi + (t >> 3) - TP);
  int rx = refl8(wj + (t & 7) - LP);
  int pix = ry * 8 + rx;
  float beta = log1pf(__expf(pbeta[0])) + 1e-6f;

  const float* qxb = qkvx + (size_t)(b * 1536 + head * DH) * 64;
  const float* kxb = qkvx + (size_t)(b * 1536 + 512 + head * DH) * 64;
  const float* vxb = qkvx + (size_t)(b * 1536 + 1024 + head * DH) * 64;
  const float* qzb = qkz + (size_t)(b * 1024 + head * DH) * 64;
  const float* kzb = qkz + (size_t)(b * 1024 + 512 + head * DH) * 64;

  float dots[16];
#pragma unroll
  for (int s = 0; s < 16; ++s) dots[s] = 0.f;
#pragma unroll
  for (int hf = 0; hf < 2; ++hf) {
    __syncthreads();
    for (int i = 0; i < 32; ++i) {
      int dd = i * 4 + w4;
      kbuf[dd * 64 + t] = kxb[(hf * 128 + dd) * 64 + pix];
    }
    __syncthreads();
    for (int dd = 0; dd < 128; ++dd) {
      float qv = qxb[(hf * 128 + dd) * 64 + pix];
#pragma unroll
      for (int s = 0; s < 16; ++s)
        dots[s] += qv * kbuf[dd * 64 + w4 * 16 + s];
    }
  }
#pragma unroll
  for (int s = 0; s < 16; ++s) att[t * 65 + w4 * 16 + s] = dots[s];
#pragma unroll
  for (int s = 0; s < 16; ++s) dots[s] = 0.f;
#pragma unroll
  for (int hf = 0; hf < 2; ++hf) {
    __syncthreads();
    for (int i = 0; i < 32; ++i) {
      int dd = i * 4 + w4;
      kbuf[dd * 64 + t] = kzb[(hf * 128 + dd) * 64 + pix];
    }
    __syncthreads();
    for (int dd = 0; dd < 128; ++dd) {
      float qv = qzb[(hf * 128 + dd) * 64 + pix];
#pragma unroll
      for (int s = 0; s < 16; ++s)
        dots[s] += qv * kbuf[dd * 64 + w4 * 16 + s];
    }
  }
#pragma unroll
  for (int s = 0; s < 16; ++s) {
    int ii = t * 65 + w4 * 16 + s;
    att[ii] = SCALE * (att[ii] + beta * dots[s]);
  }
  __syncthreads();
  if (tid < 64) {
    float m = -1e30f;
    for (int s = 0; s < 64; ++s) m = fmaxf(m, att[tid * 65 + s]);
    float den = 0.f;
    for (int s = 0; s < 64; ++s) den += __expf(att[tid * 65 + s] - m);
    float r = 1.f / den;
    for (int s = 0; s < 64; ++s) att[tid * 65 + s] = __expf(att[tid * 65 + s] - m) * r;
  }
  float acc[64];
#pragma unroll
  for (int j = 0; j < 64; ++j) acc[j] = 0.f;
#pragma unroll
  for (int hf = 0; hf < 2; ++hf) {
    __syncthreads();
    for (int i = 0; i < 32; ++i) {
      int dd = i * 4 + w4;
      kbuf[dd * 64 + t] = vxb[(hf * 128 + dd) * 64 + pix];
    }
    __syncthreads();
    for (int s = 0; s < 64; ++s) {
      float av = att[t * 65 + s];
#pragma unroll
      for (int j = 0; j < 32; ++j)
        acc[hf * 32 + j] += av * kbuf[(w4 * 32 + j) * 64 + s];
    }
  }
  unsigned short* dst = qgb + ((size_t)((b * HEADS + head) * LTOT + win * 64 + t)) * DH;
#pragma unroll
  for (int j = 0; j < 32; ++j) {
    dst[w4 * 32 + j] = (unsigned short)bf16rne(acc[j]);
    dst[128 + w4 * 32 + j] = (unsigned short)bf16rne(acc[32 + j]);
  }
}

// Global flash attention with MFMA: og = softmax(qg qg^T * scale) qg per (b,h)
// 4 waves/block, 16 queries/wave, K-tiles of 32.
__global__ __launch_bounds__(256) void gattn_mfma(
    const unsigned short* __restrict__ qgb, float* __restrict__ og) {
  __shared__ unsigned short krow[32 * 256];   // row-major, XOR-swizzled (16KB)
  __shared__ unsigned short vt[256 * 40];     // transposed, stride 40 u16 (20KB)
  __shared__ unsigned short plds[4 * 16 * 40];// per-wave P, stride 40 u16 (5KB)
  int bh = blockIdx.x >> 6;
  int qtile = (blockIdx.x & 63) * 64;
  int tid = threadIdx.x;
  int wave = tid >> 6;
  int lane = tid & 63;
  int lrow = lane & 15;
  int g = lane >> 4;
  const unsigned short* base = qgb + (size_t)bh * LTOT * DH;
  char* krowc = (char*)krow;
  char* vtc = (char*)vt;
  char* plc = (char*)plds + wave * 16 * 80;

  // Q fragments: query = qtile + wave*16 + lrow, k-dims g*8 + 32*s
  int qi = qtile + wave * 16 + lrow;
  bf16x8 qf[8];
#pragma unroll
  for (int s = 0; s < 8; ++s)
    qf[s] = *(const bf16x8*)(base + (size_t)qi * DH + s * 32 + g * 8);

  f32x4 acc[16];
#pragma unroll
  for (int f = 0; f < 16; ++f) acc[f] = (f32x4){0.f, 0.f, 0.f, 0.f};
  float m = -1e30f, l = 0.f;

  for (int kt = 0; kt < 128; ++kt) {
    const unsigned short* kb = base + (size_t)kt * 32 * DH;
    __syncthreads();
    // ---- stage K row-major swizzled (coalesced reads) ----
#pragma unroll
    for (int i = 0; i < 4; ++i) {
      int key = (tid >> 5) + 8 * i;
      int db = tid & 31;
      bf16x8 v = *(const bf16x8*)(kb + key * DH + db * 8);
      *(bf16x8*)(krowc + key * 512 + ((db * 16) ^ ((key & 7) << 4))) = v;
    }
    // ---- stage V transposed (pack 4 keys/dim into b64 writes) ----
    {
      int ku = tid & 7;
      int du = tid >> 3;
      const unsigned short* r0 = kb + (ku * 4 + 0) * DH + du * 8;
      const unsigned short* r1 = kb + (ku * 4 + 1) * DH + du * 8;
      const unsigned short* r2 = kb + (ku * 4 + 2) * DH + du * 8;
      const unsigned short* r3 = kb + (ku * 4 + 3) * DH + du * 8;
      uint4 a0 = *(const uint4*)r0;
      uint4 a1 = *(const uint4*)r1;
      uint4 a2 = *(const uint4*)r2;
      uint4 a3 = *(const uint4*)r3;
      const unsigned int* w0 = (const unsigned int*)&a0;
      const unsigned int* w1 = (const unsigned int*)&a1;
      const unsigned int* w2 = (const unsigned int*)&a2;
      const unsigned int* w3 = (const unsigned int*)&a3;
#pragma unroll
      for (int j = 0; j < 8; ++j) {
        int w = j >> 1, hi = j & 1;
        unsigned int e0 = hi ? (w0[w] >> 16) : (w0[w] & 0xffffu);
        unsigned int e1 = hi ? (w1[w] & 0xffff0000u) : (w1[w] << 16);
        unsigned int e2 = hi ? (w2[w] >> 16) : (w2[w] & 0xffffu);
        unsigned int e3 = hi ? (w3[w] & 0xffff0000u) : (w3[w] << 16);
        uint2 pk;
        pk.x = e0 | e1;
        pk.y = e2 | e3;
        *(uint2*)(vtc + (du * 8 + j) * 80 + ku * 8) = pk;
      }
    }
    __syncthreads();
    // ---- S^T = K * Q^T  (16 MFMAs) ----
    f32x4 st0 = (f32x4){0.f, 0.f, 0.f, 0.f};
    f32x4 st1 = (f32x4){0.f, 0.f, 0.f, 0.f};
    {
      int key0 = lrow;
      int key1 = 16 + lrow;
#pragma unroll
      for (int s = 0; s < 8; ++s) {
        bf16x8 kf0 = *(const bf16x8*)(krowc + key0 * 512 + (((g * 8 + 32 * s) * 2) ^ ((key0 & 7) << 4)));
        st0 = __builtin_amdgcn_mfma_f32_16x16x32_bf16(kf0, qf[s], st0, 0, 0, 0);
      }
#pragma unroll
      for (int s = 0; s < 8; ++s) {
        bf16x8 kf1 = *(const bf16x8*)(krowc + key1 * 512 + (((g * 8 + 32 * s) * 2) ^ ((key1 & 7) << 4)));
        st1 = __builtin_amdgcn_mfma_f32_16x16x32_bf16(kf1, qf[s], st1, 0, 0, 0);
      }
    }
    // ---- online softmax (keys local in regs + across lane groups) ----
    float p[8];
    float tmax = -1e30f;
#pragma unroll
    for (int r = 0; r < 4; ++r) {
      tmax = fmaxf(tmax, st0[r]);
      tmax = fmaxf(tmax, st1[r]);
    }
    tmax = fmaxf(tmax, __shfl_xor(tmax, 16, 64));
    tmax = fmaxf(tmax, __shfl_xor(tmax, 32, 64));
    float mn = fmaxf(m, tmax * SCALE);
    float corr = __expf(m - mn);
    float psum = 0.f;
#pragma unroll
    for (int r = 0; r < 4; ++r) {
      p[r] = __expf(st0[r] * SCALE - mn);
      p[4 + r] = __expf(st1[r] * SCALE - mn);
      psum += p[r] + p[4 + r];
    }
    psum += __shfl_xor(psum, 16, 64);
    psum += __shfl_xor(psum, 32, 64);
    l = l * corr + psum;
    m = mn;
    // ---- write P^T (bf16) to per-wave LDS: plds[query][key] ----
    {
      uint2 pk0, pk1;
      pk0.x = bf16rne(p[0]) | (bf16rne(p[1]) << 16);
      pk0.y = bf16rne(p[2]) | (bf16rne(p[3]) << 16);
      pk1.x = bf16rne(p[4]) | (bf16rne(p[5]) << 16);
      pk1.y = bf16rne(p[6]) | (bf16rne(p[7]) << 16);
      *(uint2*)(plc + lrow * 80 + 0 * 32 + g * 8) = pk0;
      *(uint2*)(plc + lrow * 80 + 1 * 32 + g * 8) = pk1;
    }
    asm volatile("s_waitcnt lgkmcnt(0)" ::: "memory");
    // ---- O^T += V^T * P  (16 MFMAs), with rescale ----
    bf16x8 pf = *(const bf16x8*)(plc + lrow * 80 + g * 16);
#pragma unroll
    for (int f = 0; f < 16; ++f) {
      int dim = f * 16 + lrow;
      bf16x8 vf = *(const bf16x8*)(vtc + dim * 80 + g * 16);
      acc[f][0] *= corr; acc[f][1] *= corr; acc[f][2] *= corr; acc[f][3] *= corr;
      acc[f] = __builtin_amdgcn_mfma_f32_16x16x32_bf16(vf, pf, acc[f], 0, 0, 0);
    }
  }
  // ---- epilogue: divide by l, store O (og[bh][query][dim], fp32) ----
  float r = 1.f / l;
  float* dst = og + (size_t)bh * LTOT * DH + (size_t)qi * DH;
#pragma unroll
  for (int f = 0; f < 16; ++f) {
    f32x4 o;
    o[0] = acc[f][0] * r; o[1] = acc[f][1] * r;
    o[2] = acc[f][2] * r; o[3] = acc[f][3] * r;
    *(f32x4*)(dst + f * 16 + g * 4) = o;
  }
}

// Overlap-add (gather form), divide by counts, crop -> crop (B,C,64)
__global__ __launch_bounds__(256) void overlap_kernel(
    const float* __restrict__ og, float* __restrict__ crop) {
  int idx = blockIdx.x * 256 + threadIdx.x;
  int dim = idx & 255;
  int r = idx >> 8;
  int p = r & 63;
  int head = (r >> 6) & 1;
  int b = r >> 7;
  int y = p >> 3, x = p & 7;
  int py = y + TP, px = x + LP;
  int i0 = max(0, py - 7), i1 = min(7, py);
  int j0 = max(0, px - 7), j1 = min(7, px);
  float s = 0.f;
  const float* basep = og + (size_t)(b * HEADS + head) * LTOT * DH;
  for (int iw = i0; iw <= i1; ++iw)
    for (int jw = j0; jw <= j1; ++jw) {
      int tok = (py - iw) * 8 + (px - jw);
      s += basep[(size_t)((iw * 8 + jw) * 64 + tok) * DH + dim];
    }
  float cnt = (float)((i1 - i0 + 1) * (j1 - j0 + 1));
  crop[((size_t)b * CC + head * DH + dim) * 64 + p] = s / (cnt + 1e-6f);
}

// out = x_feat + a * (Wproj @ crop + bproj)
__global__ __launch_bounds__(256) void final_kernel(
    const float* __restrict__ crop, const float* __restrict__ Wp,
    const float* __restrict__ bp, const float* __restrict__ x_feat,
    const float* __restrict__ pa, float* __restrict__ out) {
  int blocksPerB = CC >> 2;
  int b = blockIdx.x / blocksPerB;
  int ob = blockIdx.x - b * blocksPerB;
  int o = ob * 4 + (threadIdx.x >> 6);
  int p = threadIdx.x & 63;
  float a = 2.f / (1.f + __expf(-pa[0]));
  const float* xb = crop + (size_t)b * CC * 64;
  const float* wr = Wp + (size_t)o * CC;
  float acc = 0.f;
#pragma unroll 8
  for (int c = 0; c < CC; ++c) acc += wr[c] * xb[c * 64 + p];
  size_t oi = ((size_t)b * CC + o) * 64 + p;
  out[oi] = x_feat[oi] + a * (acc + bp[o]);
}

extern "C" void kernel_launch(void* const* d_in, const int* in_sizes, int n_in,
                              void* d_out, int out_size, void* d_ws, size_t ws_size,
                              hipStream_t stream) {
  const float* x_feat = (const float*)d_in[0];
  const float* z_feat = (const float*)d_in[1];
  const float* Wqkv = (const float*)d_in[2];
  const float* bqkv = (const float*)d_in[3];
  const float* Wqkz = (const float*)d_in[4];
  const float* bqkz = (const float*)d_in[5];
  const float* Wproj = (const float*)d_in[6];
  const float* bproj = (const float*)d_in[7];
  const float* pa = (const float*)d_in[8];
  const float* pbeta = (const float*)d_in[9];
  float* ws = (float*)d_ws;
  float* qkvx = ws;                          // 196608 f
  float* qkz = ws + 196608;                  // 131072 f
  unsigned short* qgb = (unsigned short*)(ws + 327680);  // 4194304 bf16 = 2097152 f
  float* og = ws + 327680 + 2097152;         // 4194304 f
  float* crop = ws + 327680 + 2097152 + 4194304;  // 65536 f
  float* out = (float*)d_out;

  conv1x1_kernel<<<BB * (1536 / 4), 256, 0, stream>>>(x_feat, Wqkv, bqkv, qkvx, 1536);
  conv1x1_kernel<<<BB * (1024 / 4), 256, 0, stream>>>(z_feat, Wqkz, bqkz, qkz, 1024);
  local_attn_kernel<<<256, 256, 0, stream>>>(qkvx, qkz, pbeta, qgb);
  gattn_mfma<<<256, 256, 0, stream>>>(qgb, og);
  overlap_kernel<<<256, 256, 0, stream>>>(og, crop);
  final_kernel<<<BB * (CC / 4), 256, 0, stream>>>(crop, Wproj, bproj, x_feat, pa, out);
}

// Round 3
// 303.019 us; speedup vs baseline: 6.0306x; 1.3968x over previous
//
#include <hip/hip_runtime.h>
#include <math.h>

#define BB 2
#define CC 512
#define HEADS 2
#define DH 256
#define NWIN 64
#define LTOT 4096
#define TP 3
#define LP 3
#define SCALE 0.0625f

typedef short bf16x8 __attribute__((ext_vector_type(8)));
typedef float f32x4 __attribute__((ext_vector_type(4)));

__device__ __forceinline__ int refl8(int v) {
  v = v < 0 ? -v : v;
  return v >= 8 ? 14 - v : v;
}

__device__ __forceinline__ unsigned int bf16rne(float x) {
  unsigned int u = __float_as_uint(x);
  return (u + 0x7fffu + ((u >> 16) & 1u)) >> 16;
}

__device__ __forceinline__ float bf2f(unsigned short u) {
  return __uint_as_float(((unsigned int)u) << 16);
}

// Y[b,o,p] = sum_c W[o,c] * X[b,c,p] + bias[o]
__global__ __launch_bounds__(256) void conv1x1_kernel(
    const float* __restrict__ X, const float* __restrict__ Wm,
    const float* __restrict__ bias, float* __restrict__ Y, int Cout) {
  int blocksPerB = Cout >> 2;
  int b = blockIdx.x / blocksPerB;
  int ob = blockIdx.x - b * blocksPerB;
  int o = ob * 4 + (threadIdx.x >> 6);
  int p = threadIdx.x & 63;
  const float* xb = X + (size_t)b * CC * 64;
  const float* wr = Wm + (size_t)o * CC;
  float acc = 0.f;
#pragma unroll 8
  for (int c = 0; c < CC; ++c) acc += wr[c] * xb[c * 64 + p];
  Y[((size_t)b * Cout + o) * 64 + p] = acc + bias[o];
}

// One block per (b, win, head). Local window attention.
// Emits qgb (B,h,L,d) row-major bf16 AND qgT (B,h,d,L) dim-major bf16.
__global__ __launch_bounds__(256) void local_attn_kernel(
    const float* __restrict__ qkvx, const float* __restrict__ qkz,
    const float* __restrict__ pbeta, unsigned short* __restrict__ qgb,
    unsigned short* __restrict__ qgT) {
  __shared__ float kbuf[128 * 64];
  __shared__ float att[64 * 65];
  int bid = blockIdx.x;
  int b = bid >> 7;
  int win = (bid & 127) >> 1;
  int head = bid & 1;
  int tid = threadIdx.x;
  int t = tid & 63;
  int w4 = tid >> 6;
  int wi = win >> 3, wj = win & 7;
  int ry = refl8(wi + (t >> 3) - TP);
  int rx = refl8(wj + (t & 7) - LP);
  int pix = ry * 8 + rx;
  float beta = log1pf(__expf(pbeta[0])) + 1e-6f;

  const float* qxb = qkvx + (size_t)(b * 1536 + head * DH) * 64;
  const float* kxb = qkvx + (size_t)(b * 1536 + 512 + head * DH) * 64;
  const float* vxb = qkvx + (size_t)(b * 1536 + 1024 + head * DH) * 64;
  const float* qzb = qkz + (size_t)(b * 1024 + head * DH) * 64;
  const float* kzb = qkz + (size_t)(b * 1024 + 512 + head * DH) * 64;

  float dots[16];
#pragma unroll
  for (int s = 0; s < 16; ++s) dots[s] = 0.f;
#pragma unroll
  for (int hf = 0; hf < 2; ++hf) {
    __syncthreads();
    for (int i = 0; i < 32; ++i) {
      int dd = i * 4 + w4;
      kbuf[dd * 64 + t] = kxb[(hf * 128 + dd) * 64 + pix];
    }
    __syncthreads();
    for (int dd = 0; dd < 128; ++dd) {
      float qv = qxb[(hf * 128 + dd) * 64 + pix];
#pragma unroll
      for (int s = 0; s < 16; ++s)
        dots[s] += qv * kbuf[dd * 64 + w4 * 16 + s];
    }
  }
#pragma unroll
  for (int s = 0; s < 16; ++s) att[t * 65 + w4 * 16 + s] = dots[s];
#pragma unroll
  for (int s = 0; s < 16; ++s) dots[s] = 0.f;
#pragma unroll
  for (int hf = 0; hf < 2; ++hf) {
    __syncthreads();
    for (int i = 0; i < 32; ++i) {
      int dd = i * 4 + w4;
      kbuf[dd * 64 + t] = kzb[(hf * 128 + dd) * 64 + pix];
    }
    __syncthreads();
    for (int dd = 0; dd < 128; ++dd) {
      float qv = qzb[(hf * 128 + dd) * 64 + pix];
#pragma unroll
      for (int s = 0; s < 16; ++s)
        dots[s] += qv * kbuf[dd * 64 + w4 * 16 + s];
    }
  }
#pragma unroll
  for (int s = 0; s < 16; ++s) {
    int ii = t * 65 + w4 * 16 + s;
    att[ii] = SCALE * (att[ii] + beta * dots[s]);
  }
  __syncthreads();
  if (tid < 64) {
    float m = -1e30f;
    for (int s = 0; s < 64; ++s) m = fmaxf(m, att[tid * 65 + s]);
    float den = 0.f;
    for (int s = 0; s < 64; ++s) den += __expf(att[tid * 65 + s] - m);
    float r = 1.f / den;
    for (int s = 0; s < 64; ++s) att[tid * 65 + s] = __expf(att[tid * 65 + s] - m) * r;
  }
  float acc[64];
#pragma unroll
  for (int j = 0; j < 64; ++j) acc[j] = 0.f;
#pragma unroll
  for (int hf = 0; hf < 2; ++hf) {
    __syncthreads();
    for (int i = 0; i < 32; ++i) {
      int dd = i * 4 + w4;
      kbuf[dd * 64 + t] = vxb[(hf * 128 + dd) * 64 + pix];
    }
    __syncthreads();
    for (int s = 0; s < 64; ++s) {
      float av = att[t * 65 + s];
#pragma unroll
      for (int j = 0; j < 32; ++j)
        acc[hf * 32 + j] += av * kbuf[(w4 * 32 + j) * 64 + s];
    }
  }
  int bh = b * HEADS + head;
  unsigned short* dst = qgb + ((size_t)(bh * LTOT + win * 64 + t)) * DH;
  unsigned short* dstT = qgT + (size_t)bh * DH * LTOT + (size_t)win * 64 + t;
#pragma unroll
  for (int j = 0; j < 32; ++j) {
    int d0 = w4 * 32 + j;
    unsigned short v0 = (unsigned short)bf16rne(acc[j]);
    unsigned short v1 = (unsigned short)bf16rne(acc[32 + j]);
    dst[d0] = v0;
    dst[128 + d0] = v1;
    dstT[(size_t)d0 * LTOT] = v0;
    dstT[(size_t)(128 + d0) * LTOT] = v1;
  }
}

// Global flash attention, split-K 2-way. Each block: 64 queries x 64 key-tiles.
// Outputs unnormalized partial O (bf16) + per-q (m,l).
__global__ __launch_bounds__(256) void gattn_mfma(
    const unsigned short* __restrict__ qgb, const unsigned short* __restrict__ qgT,
    unsigned short* __restrict__ ogp, float2* __restrict__ ml) {
  __shared__ unsigned short krow[32 * 256];  // row-major keys, XOR-swizzled (16KB)
  __shared__ unsigned short vt[256 * 32];    // [dim][key] from qgT (16KB)
  __shared__ unsigned short plds[4 * 16 * 40];
  int split = blockIdx.x & 1;
  int qt = (blockIdx.x >> 1) & 63;
  int bh = blockIdx.x >> 7;
  int qtile = qt * 64;
  int tid = threadIdx.x;
  int wave = tid >> 6;
  int lane = tid & 63;
  int lrow = lane & 15;
  int g = lane >> 4;
  const unsigned short* base = qgb + (size_t)bh * LTOT * DH;
  const unsigned short* baseT = qgT + (size_t)bh * DH * LTOT;
  char* krowc = (char*)krow;
  char* vtc = (char*)vt;
  char* plc = (char*)plds + wave * 16 * 80;

  int qi = qtile + wave * 16 + lrow;
  bf16x8 qf[8];
#pragma unroll
  for (int s = 0; s < 8; ++s)
    qf[s] = *(const bf16x8*)(base + (size_t)qi * DH + s * 32 + g * 8);

  f32x4 acc[16];
#pragma unroll
  for (int f = 0; f < 16; ++f) acc[f] = (f32x4){0.f, 0.f, 0.f, 0.f};
  float m = -1e30f, l = 0.f;

  for (int kt = split * 64; kt < split * 64 + 64; ++kt) {
    const unsigned short* kb = base + (size_t)kt * 32 * DH;
    __syncthreads();
    // ---- stage K row-major swizzled ----
#pragma unroll
    for (int i = 0; i < 4; ++i) {
      int key = (tid >> 5) + 8 * i;
      int db = tid & 31;
      bf16x8 v = *(const bf16x8*)(kb + key * DH + db * 8);
      *(bf16x8*)(krowc + key * 512 + ((db * 16) ^ ((key & 7) << 4))) = v;
    }
    // ---- stage V [dim][key] from pre-transposed qgT (conflict-free b128) ----
#pragma unroll
    for (int i = 0; i < 4; ++i) {
      int dim = i * 64 + (tid >> 2);
      int ch = tid & 3;
      bf16x8 v = *(const bf16x8*)(baseT + (size_t)dim * LTOT + kt * 32 + ch * 8);
      *(bf16x8*)(vtc + dim * 64 + ch * 16) = v;
    }
    __syncthreads();
    // ---- S^T = K * Q^T (16 MFMAs, 4 independent chains) ----
    f32x4 s0a = (f32x4){0.f, 0.f, 0.f, 0.f}, s0b = s0a, s1a = s0a, s1b = s0a;
    int key0 = lrow, key1 = 16 + lrow;
#pragma unroll
    for (int s = 0; s < 4; ++s) {
      bf16x8 k0 = *(const bf16x8*)(krowc + key0 * 512 + (((g * 8 + 32 * s) * 2) ^ ((key0 & 7) << 4)));
      s0a = __builtin_amdgcn_mfma_f32_16x16x32_bf16(k0, qf[s], s0a, 0, 0, 0);
      bf16x8 k0b = *(const bf16x8*)(krowc + key0 * 512 + (((g * 8 + 32 * (s + 4)) * 2) ^ ((key0 & 7) << 4)));
      s0b = __builtin_amdgcn_mfma_f32_16x16x32_bf16(k0b, qf[s + 4], s0b, 0, 0, 0);
      bf16x8 k1 = *(const bf16x8*)(krowc + key1 * 512 + (((g * 8 + 32 * s) * 2) ^ ((key1 & 7) << 4)));
      s1a = __builtin_amdgcn_mfma_f32_16x16x32_bf16(k1, qf[s], s1a, 0, 0, 0);
      bf16x8 k1b = *(const bf16x8*)(krowc + key1 * 512 + (((g * 8 + 32 * (s + 4)) * 2) ^ ((key1 & 7) << 4)));
      s1b = __builtin_amdgcn_mfma_f32_16x16x32_bf16(k1b, qf[s + 4], s1b, 0, 0, 0);
    }
    f32x4 st0 = s0a + s0b;
    f32x4 st1 = s1a + s1b;
    // ---- online softmax with deferred rescale (thr=6) ----
    float tmax = -1e30f;
#pragma unroll
    for (int r = 0; r < 4; ++r) {
      tmax = fmaxf(tmax, st0[r]);
      tmax = fmaxf(tmax, st1[r]);
    }
    tmax = fmaxf(tmax, __shfl_xor(tmax, 16, 64));
    tmax = fmaxf(tmax, __shfl_xor(tmax, 32, 64));
    float sm = tmax * SCALE;
    if (__any(sm > m + 6.f)) {
      float mn = fmaxf(m, sm);
      float corr = __expf(m - mn);
#pragma unroll
      for (int f = 0; f < 16; ++f) {
        acc[f][0] *= corr; acc[f][1] *= corr;
        acc[f][2] *= corr; acc[f][3] *= corr;
      }
      l *= corr;
      m = mn;
    }
    float p[8];
    float psum = 0.f;
#pragma unroll
    for (int r = 0; r < 4; ++r) {
      p[r] = __expf(st0[r] * SCALE - m);
      p[4 + r] = __expf(st1[r] * SCALE - m);
      psum += p[r] + p[4 + r];
    }
    psum += __shfl_xor(psum, 16, 64);
    psum += __shfl_xor(psum, 32, 64);
    l += psum;
    // ---- write P^T (bf16) to per-wave LDS: plds[query][key] ----
    {
      uint2 pk0, pk1;
      pk0.x = bf16rne(p[0]) | (bf16rne(p[1]) << 16);
      pk0.y = bf16rne(p[2]) | (bf16rne(p[3]) << 16);
      pk1.x = bf16rne(p[4]) | (bf16rne(p[5]) << 16);
      pk1.y = bf16rne(p[6]) | (bf16rne(p[7]) << 16);
      *(uint2*)(plc + lrow * 80 + 0 * 32 + g * 8) = pk0;
      *(uint2*)(plc + lrow * 80 + 1 * 32 + g * 8) = pk1;
    }
    asm volatile("s_waitcnt lgkmcnt(0)" ::: "memory");
    // ---- O^T += V^T * P (16 MFMAs) ----
    bf16x8 pf = *(const bf16x8*)(plc + lrow * 80 + g * 16);
#pragma unroll
    for (int f = 0; f < 16; ++f) {
      int dim = f * 16 + lrow;
      bf16x8 vf = *(const bf16x8*)(vtc + dim * 64 + g * 16);
      acc[f] = __builtin_amdgcn_mfma_f32_16x16x32_bf16(vf, pf, acc[f], 0, 0, 0);
    }
  }
  // ---- epilogue: store unnormalized partial O as bf16 + (m,l) ----
  unsigned short* dstp = ogp + ((size_t)(split * 4 + bh) * LTOT + qi) * DH;
#pragma unroll
  for (int f = 0; f < 16; ++f) {
    uint2 pk;
    pk.x = bf16rne(acc[f][0]) | (bf16rne(acc[f][1]) << 16);
    pk.y = bf16rne(acc[f][2]) | (bf16rne(acc[f][3]) << 16);
    *(uint2*)(dstp + f * 16 + g * 4) = pk;
  }
  if (g == 0) ml[(size_t)(split * 4 + bh) * LTOT + qi] = make_float2(m, l);
}

// Per-query combine weights for the 2 key-splits.
__global__ __launch_bounds__(256) void comb_kernel(
    const float2* __restrict__ ml, float2* __restrict__ comb) {
  int idx = blockIdx.x * 256 + threadIdx.x;  // 16384
  float2 a = ml[idx];
  float2 b = ml[16384 + idx];
  float M = fmaxf(a.x, b.x);
  float w0 = __expf(a.x - M), w1 = __expf(b.x - M);
  float r = 1.f / (a.y * w0 + b.y * w1);
  comb[idx] = make_float2(w0 * r, w1 * r);
}

// Combine splits + overlap-add gather + crop -> crop (B,C,64)
__global__ __launch_bounds__(256) void overlap_kernel(
    const unsigned short* __restrict__ ogp, const float2* __restrict__ comb,
    float* __restrict__ crop) {
  int idx = blockIdx.x * 256 + threadIdx.x;
  int dim = idx & 255;
  int r = idx >> 8;
  int p = r & 63;
  int head = (r >> 6) & 1;
  int b = r >> 7;
  int bh = b * 2 + head;
  int y = p >> 3, x = p & 7;
  int py = y + TP, px = x + LP;
  int i0 = max(0, py - 7), i1 = min(7, py);
  int j0 = max(0, px - 7), j1 = min(7, px);
  float s = 0.f;
  for (int iw = i0; iw <= i1; ++iw)
    for (int jw = j0; jw <= j1; ++jw) {
      int tok = (py - iw) * 8 + (px - jw);
      int q = (iw * 8 + jw) * 64 + tok;
      float2 cb = comb[bh * 4096 + q];
      size_t e = ((size_t)bh * 4096 + q) * 256 + dim;
      float o0 = bf2f(ogp[e]);
      float o1 = bf2f(ogp[(size_t)4 * LTOT * DH + e]);
      s += cb.x * o0 + cb.y * o1;
    }
  float cnt = (float)((i1 - i0 + 1) * (j1 - j0 + 1));
  crop[((size_t)b * CC + head * DH + dim) * 64 + p] = s / (cnt + 1e-6f);
}

// out = x_feat + a * (Wproj @ crop + bproj)
__global__ __launch_bounds__(256) void final_kernel(
    const float* __restrict__ crop, const float* __restrict__ Wp,
    const float* __restrict__ bp, const float* __restrict__ x_feat,
    const float* __restrict__ pa, float* __restrict__ out) {
  int blocksPerB = CC >> 2;
  int b = blockIdx.x / blocksPerB;
  int ob = blockIdx.x - b * blocksPerB;
  int o = ob * 4 + (threadIdx.x >> 6);
  int p = threadIdx.x & 63;
  float a = 2.f / (1.f + __expf(-pa[0]));
  const float* xb = crop + (size_t)b * CC * 64;
  const float* wr = Wp + (size_t)o * CC;
  float acc = 0.f;
#pragma unroll 8
  for (int c = 0; c < CC; ++c) acc += wr[c] * xb[c * 64 + p];
  size_t oi = ((size_t)b * CC + o) * 64 + p;
  out[oi] = x_feat[oi] + a * (acc + bp[o]);
}

extern "C" void kernel_launch(void* const* d_in, const int* in_sizes, int n_in,
                              void* d_out, int out_size, void* d_ws, size_t ws_size,
                              hipStream_t stream) {
  const float* x_feat = (const float*)d_in[0];
  const float* z_feat = (const float*)d_in[1];
  const float* Wqkv = (const float*)d_in[2];
  const float* bqkv = (const float*)d_in[3];
  const float* Wqkz = (const float*)d_in[4];
  const float* bqkz = (const float*)d_in[5];
  const float* Wproj = (const float*)d_in[6];
  const float* bproj = (const float*)d_in[7];
  const float* pa = (const float*)d_in[8];
  const float* pbeta = (const float*)d_in[9];
  float* ws = (float*)d_ws;
  // ws layout (floats), total 8781824 f = 35.1 MB (same footprint as round 0):
  float* qkvx = ws;                                        // 196608
  float* qkz = ws + 196608;                                // 131072
  unsigned short* qgb = (unsigned short*)(ws + 327680);    // 2097152 f
  unsigned short* qgT = (unsigned short*)(ws + 2424832);   // 2097152 f
  unsigned short* ogp = (unsigned short*)(ws + 4521984);   // 4194304 f (2 splits bf16)
  float2* ml = (float2*)(ws + 8716288);                    // 65536 f
  float* crop = ws;                                        // alias qkvx (dead after local_attn)
  float2* comb = (float2*)(ws + 196608);                   // alias qkz (dead after local_attn)
  float* out = (float*)d_out;

  conv1x1_kernel<<<BB * (1536 / 4), 256, 0, stream>>>(x_feat, Wqkv, bqkv, qkvx, 1536);
  conv1x1_kernel<<<BB * (1024 / 4), 256, 0, stream>>>(z_feat, Wqkz, bqkz, qkz, 1024);
  local_attn_kernel<<<256, 256, 0, stream>>>(qkvx, qkz, pbeta, qgb, qgT);
  gattn_mfma<<<512, 256, 0, stream>>>(qgb, qgT, ogp, ml);
  comb_kernel<<<64, 256, 0, stream>>>(ml, comb);
  overlap_kernel<<<256, 256, 0, stream>>>(ogp, comb, crop);
  final_kernel<<<BB * (CC / 4), 256, 0, stream>>>(crop, Wproj, bproj, x_feat, pa, out);
}